// Round 6
// baseline (417.236 us; speedup 1.0000x reference)
//
#include <hip/hip_runtime.h>
#include <hip/hip_bf16.h>
#include <stdint.h>

#define BG 64     // graphs
#define NP 256    // nodes per graph
#define DI 256    // in features
#define DO 128    // out features = clusters
#define EP 8192   // edges per graph

// ALL float tensors are FP32 (R8 probe-decoded). Edges int32 (+int64 vote).

typedef __attribute__((ext_vector_type(8))) short short8;   // 8 bf16 (4 VGPRs)
typedef __attribute__((ext_vector_type(4))) short short4v;  // 4 bf16 (8 B)
typedef __attribute__((ext_vector_type(4))) float float4v;  // MFMA accumulator

__device__ __forceinline__ int ldi(const void* p, size_t i, int i64) {
  return i64 ? (int)((const long long*)p)[i] : ((const int*)p)[i];
}

// fp32 -> bf16 bits, round-to-nearest-even
__device__ __forceinline__ short f2b(float x) {
  union { float f; unsigned u; } c; c.f = x;
  unsigned r = c.u + 0x7FFFu + ((c.u >> 16) & 1u);
  return (short)(r >> 16);
}
__device__ __forceinline__ float b2f(short b) {
  union { unsigned u; float f; } c; c.u = ((unsigned)(unsigned short)b) << 16;
  return c.f;
}

// uniform int64-vs-int32 vote: upper words of first 8 int64 values are all 0 for int64
// data; for int32 data they are random edge values -> P(all zero) = 2^-64.
__device__ __forceinline__ int vote_i64(const void* esrc) {
  const uint32_t* ew = (const uint32_t*)esrc;
  int i64 = 1;
#pragma unroll
  for (int j = 0; j < 8; ++j)
    if (ew[2 * j + 1] != 0) i64 = 0;
  return i64;
}

// zero 16 adj rows starting at r0, skipping each row's diagonal 128-col block
// (the diagonal is written by pool_core -- disjoint addresses, order-independent).
__device__ __forceinline__ void fill_adj_rows(float* __restrict__ adj, int r0) {
  int t = threadIdx.x;
  const float4v z = {0.f, 0.f, 0.f, 0.f};
  for (int rr = 0; rr < 16; ++rr) {
    int r = r0 + rr;
    int g = r >> 7;                      // graph of this row
    float4v* row = (float4v*)(adj + (size_t)r * (BG * DO));
    int s0 = g * 32;                     // diag float4-range [s0, s0+32)
#pragma unroll
    for (int it = 0; it < 8; ++it) {
      int p = it * 256 + t;
      if ((unsigned)(p - s0) >= 32u)
        __builtin_nontemporal_store(z, &row[p]);
    }
  }
}

// out = P^T @ Y (64x64 tile), 3-term hi/lo (hh+lh+hl). Shared by adj-diag and hpool.
__device__ __forceinline__ void pool_core(const short* __restrict__ PtHb,
                                          const short* __restrict__ PtLb,
                                          const short* __restrict__ YHb,
                                          const short* __restrict__ YLb,
                                          float* __restrict__ outb, int ld,
                                          int ch2, int rh) {
  int t = threadIdx.x, wave = t >> 6, lane = t & 63;
  int m = lane & 15, q = lane >> 4;
  float4v acc[4];
#pragma unroll
  for (int i = 0; i < 4; ++i) acc[i] = (float4v){0.f, 0.f, 0.f, 0.f};
  int irow = rh * 64 + wave * 16 + m;
  const short* pah = &PtHb[(size_t)irow * NP];
  const short* pal = &PtLb[(size_t)irow * NP];
  for (int kc = 0; kc < NP; kc += 32) {
    short8 ah = *(const short8*)&pah[kc + q * 8];
    short8 al = *(const short8*)&pal[kc + q * 8];
#pragma unroll
    for (int tt = 0; tt < 4; ++tt) {
      int j = ch2 * 64 + tt * 16 + m;
      short8 bh = *(const short8*)&YHb[(size_t)j * NP + kc + q * 8];
      short8 bl = *(const short8*)&YLb[(size_t)j * NP + kc + q * 8];
      acc[tt] = __builtin_amdgcn_mfma_f32_16x16x32_bf16(ah, bh, acc[tt], 0, 0, 0);
      acc[tt] = __builtin_amdgcn_mfma_f32_16x16x32_bf16(al, bh, acc[tt], 0, 0, 0);
      acc[tt] = __builtin_amdgcn_mfma_f32_16x16x32_bf16(ah, bl, acc[tt], 0, 0, 0);
    }
  }
#pragma unroll
  for (int tt = 0; tt < 4; ++tt) {
#pragma unroll
    for (int reg = 0; reg < 4; ++reg) {
      int i = rh * 64 + wave * 16 + q * 4 + reg;
      int j = ch2 * 64 + tt * 16 + m;
      outb[(size_t)i * ld + j] = acc[tt][reg];
    }
  }
}

// ---- prep: fused htr (1024 blocks) + scatter (256) + wt (32); LDS union 64 KiB ----
__global__ __launch_bounds__(256) void k_prep(const float* __restrict__ h,
                                              const void* __restrict__ esrc,
                                              const void* __restrict__ edst,
                                              const float* __restrict__ Wf,
                                              const float* __restrict__ Wp,
                                              short* __restrict__ hThi,
                                              short* __restrict__ hTlo,
                                              short* __restrict__ hRhi,
                                              short* __restrict__ Abf,
                                              float* __restrict__ deg,
                                              short* __restrict__ Wt) {
  __shared__ __align__(16) char smem[65536];
  int bx = blockIdx.x, t = threadIdx.x;
  if (bx < 1024) {
    // ---- htr: hThi/hTlo[b][f][n] = bf16 hi/lo split of h[b][n][f]; hRhi row-major hi ---
    float (*T)[65] = (float(*)[65])smem;
    int b = bx >> 4, n0 = (bx & 3) * 64, f0 = ((bx >> 2) & 3) * 64;
    int r = t >> 4, c4 = (t & 15) * 4;
#pragma unroll
    for (int i = 0; i < 4; ++i) {
      size_t ridx = (size_t)b * NP + n0 + i * 16 + r;
      float4 v = *(const float4*)&h[ridx * DI + f0 + c4];
      short rh4[4] = { f2b(v.x), f2b(v.y), f2b(v.z), f2b(v.w) };
      *(short4v*)&hRhi[ridx * DI + f0 + c4] = *(short4v*)rh4;   // row-major bf16 hi
      T[i * 16 + r][c4 + 0] = v.x; T[i * 16 + r][c4 + 1] = v.y;
      T[i * 16 + r][c4 + 2] = v.z; T[i * 16 + r][c4 + 3] = v.w;
    }
    __syncthreads();
#pragma unroll
    for (int i = 0; i < 4; ++i) {
      int f = i * 16 + r;
      short hi4[4], lo4[4];
#pragma unroll
      for (int j = 0; j < 4; ++j) {
        float x = T[c4 + j][f];
        short hb = f2b(x);
        hi4[j] = hb;
        lo4[j] = f2b(x - b2f(hb));
      }
      size_t o = ((size_t)b * DI + f0 + f) * NP + n0 + c4;
      *(short4v*)&hThi[o] = *(short4v*)hi4;
      *(short4v*)&hTlo[o] = *(short4v*)lo4;
    }
  } else if (bx < 1280) {
    // ---- scatter: LDS row slab, no global atomics; exact-bf16 Abf + fp32 deg ----
    float (*Asl)[256] = (float(*)[256])smem;   // 64 KiB
    int idx = bx - 1024, b = idx >> 2, rq = idx & 3;
    float4* Az = (float4*)&Asl[0][0];
    for (int i = t; i < 64 * 256 / 4; i += 256) Az[i] = make_float4(0.f, 0.f, 0.f, 0.f);
    int i64 = vote_i64(esrc);
    __syncthreads();
    const size_t base = (size_t)b * EP;
    for (int e = t; e < EP; e += 256) {
      int si = ldi(esrc, base + e, i64) & (NP - 1);
      int di = ldi(edst, base + e, i64) & (NP - 1);
      if ((di >> 6) == rq) atomicAdd(&Asl[di & 63][si], 1.0f);
    }
    __syncthreads();
    int wv = t >> 6, ln = t & 63;
#pragma unroll
    for (int k = 0; k < 16; ++k) {
      int r = k * 4 + wv;
      float4 v = *(float4*)&Asl[r][ln * 4];
      int gr = rq * 64 + r;
      size_t o = ((size_t)b * NP + gr) * NP + ln * 4;
      short tmp[4] = { f2b(v.x), f2b(v.y), f2b(v.z), f2b(v.w) };  // counts <256: exact
      *(short4v*)&Abf[o] = *(short4v*)tmp;
      float s = v.x + v.y + v.z + v.w;
      s += __shfl_xor(s, 1);  s += __shfl_xor(s, 2);  s += __shfl_xor(s, 4);
      s += __shfl_xor(s, 8);  s += __shfl_xor(s, 16); s += __shfl_xor(s, 32);
      if (ln == 0) deg[b * NP + gr] = s;   // integer sum: fp32-exact
    }
  } else {
    // ---- wt: Wt[n][k] = bf16(W_head(n)[k][n&127]); [256][512] shorts, k-contig ----
    float (*T)[132] = (float(*)[132])smem;
    int bb = bx - 1280;          // 0..31
    int head = bb >> 4;
    int k0 = (bb & 15) * 32;
    const float* W = head ? Wp : Wf;
    {
      int k = t >> 3, fs = (t & 7) * 16;
      const float* src = &W[(size_t)(k0 + k) * DO + fs];
#pragma unroll
      for (int j = 0; j < 4; ++j)
        *(float4*)&T[k][fs + j * 4] = *(const float4*)(src + j * 4);
    }
    __syncthreads();
    int f = t & 127, kh = (t >> 7) * 16;
    __align__(16) short tmp[16];
#pragma unroll
    for (int i = 0; i < 16; ++i) tmp[i] = f2b(T[kh + i][f]);
    short* dst = &Wt[((size_t)head * DO + f) * 512 + k0 + kh];
    *(short8*)dst = *(short8*)&tmp[0];
    *(short8*)(dst + 8) = *(short8*)&tmp[8];
  }
}

// ---- fused agg+zepi (+ adj fill rows [0,4096)): per block 32 rows.
// Phase A: agg = rowscale(A@h) via MFMA hi/lo -> bf16 LDS Xa.
// Phase B: Z = [hRhi|Xa]@[Wf|Wp] MFMA (barrier-free k-loop: h-half reads global bf16
// directly in fragment layout), fused bias/norm/relu/softmax; emits transposed bf16
// hi/lo featT/assignT. LDS: union{ Xa[32][264], TT[2][2][128][40] }.
__global__ __launch_bounds__(256) void k_fz(const short* __restrict__ hRhi,
                                            const short* __restrict__ Abf,
                                            const short* __restrict__ hThi,
                                            const short* __restrict__ hTlo,
                                            const float* __restrict__ deg,
                                            const short* __restrict__ Wt,
                                            const float* __restrict__ bfe,
                                            const float* __restrict__ bpo,
                                            short* __restrict__ FtH, short* __restrict__ FtL,
                                            short* __restrict__ PtH, short* __restrict__ PtL,
                                            float* __restrict__ adj) {
  __shared__ __align__(16) char smem[40960];
  int bx = blockIdx.x, t = threadIdx.x;
  if (bx >= 512) { fill_adj_rows(adj, (bx - 512) * 16); return; }
  short (*Xa)[264] = (short(*)[264])smem;                    // 16896 B (padded rows)
  short (*TT)[2][128][40] = (short(*)[2][128][40])smem;      // 40960 B (post-barrier)
  int r0 = bx * 32;                  // global row (b*NP + node)
  int b = r0 >> 8, nl = r0 & 255;
  int wave = t >> 6, lane = t & 63;
  int rt = wave & 1, ch = wave >> 1;  // ch: f-half (phase A) / head (phase B)
  int m = lane & 15, q = lane >> 4;
  float4v acc[8];
#pragma unroll
  for (int i = 0; i < 8; ++i) acc[i] = (float4v){0.f, 0.f, 0.f, 0.f};

  // ---- phase A ----
  const short* Ar = &Abf[((size_t)r0 + rt * 16 + m) * NP];
  for (int kc = 0; kc < NP; kc += 32) {
    short8 af = *(const short8*)&Ar[kc + q * 8];
#pragma unroll
    for (int tt = 0; tt < 8; ++tt) {
      int f = ch * 128 + tt * 16 + m;
      short8 bh = *(const short8*)&hThi[((size_t)b * DI + f) * NP + kc + q * 8];
      short8 bl = *(const short8*)&hTlo[((size_t)b * DI + f) * NP + kc + q * 8];
      acc[tt] = __builtin_amdgcn_mfma_f32_16x16x32_bf16(af, bh, acc[tt], 0, 0, 0);
      acc[tt] = __builtin_amdgcn_mfma_f32_16x16x32_bf16(af, bl, acc[tt], 0, 0, 0);
    }
  }
#pragma unroll
  for (int reg = 0; reg < 4; ++reg) {
    int rowl = rt * 16 + q * 4 + reg;
    float sc = 1.0f / fmaxf(deg[r0 + rowl], 1.0f);
#pragma unroll
    for (int tt = 0; tt < 8; ++tt)
      Xa[rowl][ch * 128 + tt * 16 + m] = f2b(acc[tt][reg] * sc);  // same rounding as before
  }
  __syncthreads();

  // ---- phase B (no barriers in the k-loops) ----
#pragma unroll
  for (int i = 0; i < 8; ++i) acc[i] = (float4v){0.f, 0.f, 0.f, 0.f};
  const short* hr = &hRhi[(size_t)(r0 + rt * 16 + m) * DI];
  for (int kc = 0; kc < DI; kc += 32) {
    short8 afrag = *(const short8*)&hr[kc + q * 8];
#pragma unroll
    for (int tt = 0; tt < 8; ++tt) {
      int n = ch * 128 + tt * 16 + m;
      short8 bfrag = *(const short8*)&Wt[(size_t)n * 512 + kc + q * 8];
      acc[tt] = __builtin_amdgcn_mfma_f32_16x16x32_bf16(afrag, bfrag, acc[tt], 0, 0, 0);
    }
  }
  for (int kc = DI; kc < 2 * DI; kc += 32) {
    short8 afrag = *(const short8*)&Xa[rt * 16 + m][(kc - DI) + q * 8];
#pragma unroll
    for (int tt = 0; tt < 8; ++tt) {
      int n = ch * 128 + tt * 16 + m;
      short8 bfrag = *(const short8*)&Wt[(size_t)n * 512 + kc + q * 8];
      acc[tt] = __builtin_amdgcn_mfma_f32_16x16x32_bf16(afrag, bfrag, acc[tt], 0, 0, 0);
    }
  }
  __syncthreads();   // all Xa reads done before TT overwrites the union

  // epilogue: C/D layout col = tt*16+m, row = q*4+reg (within row-tile rt)
  const float* bp = ch ? bpo : bfe;
  float bias[8];
#pragma unroll
  for (int tt = 0; tt < 8; ++tt) bias[tt] = bp ? bp[tt * 16 + m] : 0.f;
#pragma unroll
  for (int reg = 0; reg < 4; ++reg) {
    int rloc = rt * 16 + q * 4 + reg;
    float z[8];
    float ss = 0.f;
#pragma unroll
    for (int tt = 0; tt < 8; ++tt) { z[tt] = acc[tt][reg] + bias[tt]; ss += z[tt] * z[tt]; }
    ss += __shfl_xor(ss, 1); ss += __shfl_xor(ss, 2);
    ss += __shfl_xor(ss, 4); ss += __shfl_xor(ss, 8);
    float inv = 1.0f / fmaxf(sqrtf(ss), 1e-12f);
    float v[8];
#pragma unroll
    for (int tt = 0; tt < 8; ++tt) v[tt] = fmaxf(z[tt] * inv, 0.f);
    if (ch == 1) {   // softmax head -> assign values
      float mx = v[0];
#pragma unroll
      for (int tt = 1; tt < 8; ++tt) mx = fmaxf(mx, v[tt]);
      mx = fmaxf(mx, __shfl_xor(mx, 1)); mx = fmaxf(mx, __shfl_xor(mx, 2));
      mx = fmaxf(mx, __shfl_xor(mx, 4)); mx = fmaxf(mx, __shfl_xor(mx, 8));
      float e[8], s = 0.f;
#pragma unroll
      for (int tt = 0; tt < 8; ++tt) { e[tt] = __expf(v[tt] - mx); s += e[tt]; }
      s += __shfl_xor(s, 1); s += __shfl_xor(s, 2);
      s += __shfl_xor(s, 4); s += __shfl_xor(s, 8);
      float is = 1.0f / s;
#pragma unroll
      for (int tt = 0; tt < 8; ++tt) v[tt] = e[tt] * is;
    }
#pragma unroll
    for (int tt = 0; tt < 8; ++tt) {
      short hb = f2b(v[tt]);
      short lb = f2b(v[tt] - b2f(hb));
      TT[ch][0][tt * 16 + m][rloc] = hb;
      TT[ch][1][tt * 16 + m][rloc] = lb;
    }
  }
  __syncthreads();
  // writeout: 2 head x 2 hilo x 128 col x 4 chunks(16B) = 2048 chunks, 8 per thread
#pragma unroll
  for (int it = 0; it < 8; ++it) {
    int chunk = it * 256 + t;
    int c = chunk & 3, col = (chunk >> 2) & 127;
    int hl = (chunk >> 9) & 1, head = chunk >> 10;
    short* base = head ? (hl ? PtL : PtH) : (hl ? FtL : FtH);
    short* dst = &base[((size_t)b * DO + col) * NP + nl + c * 8];
    *(short8*)dst = *(const short8*)&TT[head][hl][col][c * 8];
  }
}

// ---- AS = A @ assign via MFMA; + hpool = P^T@F (independent of AS);
// + adj fill rows [4096,6144). grid 896 = 512 AS + 256 hpool + 128 fill ----
__global__ __launch_bounds__(256) void k_gemm_as(const short* __restrict__ Abf,
                                                 const short* __restrict__ PtH,
                                                 const short* __restrict__ PtL,
                                                 const short* __restrict__ FtH,
                                                 const short* __restrict__ FtL,
                                                 short* __restrict__ AStH,
                                                 short* __restrict__ AStL,
                                                 float* __restrict__ hpool,
                                                 float* __restrict__ adj) {
  __shared__ __align__(16) short TS[2][128][40];   // 20 KiB
  int bx = blockIdx.x, t = threadIdx.x;
  if (bx >= 768) { fill_adj_rows(adj, 4096 + (bx - 768) * 16); return; }
  if (bx >= 512) {
    // hpool = P^T @ F for graph b, tile (rh, ch2)
    int idx = bx - 512, b = idx >> 2, x = idx & 3, ch2 = x & 1, rh = x >> 1;
    pool_core(&PtH[(size_t)b * DO * NP], &PtL[(size_t)b * DO * NP],
              &FtH[(size_t)b * DO * NP], &FtL[(size_t)b * DO * NP],
              &hpool[(size_t)b * DO * DO], DO, ch2, rh);
    return;
  }
  int b = bx >> 3, n0 = (bx & 7) * 32;
  int wave = t >> 6, lane = t & 63, rt = wave & 1, fh = wave >> 1;
  int m = lane & 15, q = lane >> 4;
  float4v acc[4];
#pragma unroll
  for (int i = 0; i < 4; ++i) acc[i] = (float4v){0.f, 0.f, 0.f, 0.f};
  const short* Ar = &Abf[((size_t)b * NP + n0 + rt * 16 + m) * NP];
  for (int kc = 0; kc < NP; kc += 32) {
    short8 af = *(const short8*)&Ar[kc + q * 8];
#pragma unroll
    for (int tt = 0; tt < 4; ++tt) {
      int j = fh * 64 + tt * 16 + m;
      short8 bh = *(const short8*)&PtH[((size_t)b * DO + j) * NP + kc + q * 8];
      short8 bl = *(const short8*)&PtL[((size_t)b * DO + j) * NP + kc + q * 8];
      acc[tt] = __builtin_amdgcn_mfma_f32_16x16x32_bf16(af, bh, acc[tt], 0, 0, 0);
      acc[tt] = __builtin_amdgcn_mfma_f32_16x16x32_bf16(af, bl, acc[tt], 0, 0, 0);
    }
  }
#pragma unroll
  for (int tt = 0; tt < 4; ++tt) {
#pragma unroll
    for (int reg = 0; reg < 4; ++reg) {
      int j = fh * 64 + tt * 16 + m;
      int nlr = rt * 16 + q * 4 + reg;
      float vv = acc[tt][reg];
      short hb = f2b(vv);
      TS[0][j][nlr] = hb;
      TS[1][j][nlr] = f2b(vv - b2f(hb));
    }
  }
  __syncthreads();
#pragma unroll
  for (int it = 0; it < 4; ++it) {
    int chunk = it * 256 + t;
    int c = chunk & 3, col = (chunk >> 2) & 127, hl = chunk >> 9;
    short* dst = &(hl ? AStL : AStH)[((size_t)b * DO + col) * NP + n0 + c * 8];
    *(short8*)dst = *(const short8*)&TS[hl][col][c * 8];
  }
}

// ---- adj diag = P^T @ AS (+ adj fill rows [6144,8192)). grid 384 = 256 + 128 ----
__global__ __launch_bounds__(256) void k_pool2(const short* __restrict__ PtH,
                                               const short* __restrict__ PtL,
                                               const short* __restrict__ AStH,
                                               const short* __restrict__ AStL,
                                               float* __restrict__ adj) {
  int bx = blockIdx.x;
  if (bx >= 256) { fill_adj_rows(adj, 6144 + (bx - 256) * 16); return; }
  int b = bx >> 2, x = bx & 3, ch2 = x & 1, rh = x >> 1;
  pool_core(&PtH[(size_t)b * DO * NP], &PtL[(size_t)b * DO * NP],
            &AStH[(size_t)b * DO * NP], &AStL[(size_t)b * DO * NP],
            &adj[(size_t)(b * DO) * (BG * DO) + (size_t)b * DO], BG * DO, ch2, rh);
}

extern "C" void kernel_launch(void* const* d_in, const int* in_sizes, int n_in,
                              void* d_out, int out_size, void* d_ws, size_t ws_size,
                              hipStream_t stream) {
  (void)out_size; (void)ws_size;
  int ih = -1, ie[2] = {-1, -1}, iw[2] = {-1, -1}, ib[2] = {-1, -1};
  int ne = 0, nw = 0, nb = 0;
  for (int i = 0; i < n_in; ++i) {
    long long s = in_sizes[i];
    if (s == (long long)BG * NP * DI) { if (ih < 0) ih = i; }
    else if (s == (long long)BG * EP && ne < 2) ie[ne++] = i;
    else if (s == (long long)2 * DI * DO && nw < 2) iw[nw++] = i;
    else if (s == (long long)DO && nb < 2) ib[nb++] = i;
  }
  if (ih < 0 || ne < 2 || nw < 2) {
    ih = 0;
    ie[0] = (n_in > 1) ? 1 : 0;  ie[1] = (n_in > 2) ? 2 : ie[0];
    iw[0] = (n_in > 3) ? 3 : 0;  iw[1] = (n_in > 5) ? 5 : iw[0];
    ib[0] = (n_in > 4) ? 4 : -1; ib[1] = (n_in > 6) ? 6 : -1;
    nb = (ib[1] >= 0) ? 2 : (ib[0] >= 0 ? 1 : 0);
  }
  const float* h    = (const float*)d_in[ih];
  const void* esrc  = d_in[ie[0]];
  const void* edst  = d_in[ie[1]];
  const float* Wf   = (const float*)d_in[iw[0]];
  const float* Wp   = (const float*)d_in[iw[1]];
  const float* bfe  = (nb >= 1) ? (const float*)d_in[ib[0]] : nullptr;
  const float* bpo  = (nb >= 2) ? (const float*)d_in[ib[1]] : nullptr;

  float* adj   = (float*)d_out;
  float* hpool = (float*)d_out + (size_t)(BG * DO) * (BG * DO);

  // Scratch in d_ws (~56.3 MiB; ws >= 1 GiB per harness poison fills).
  char* wb = (char*)d_ws;
  short* Abf  = (short*)wb;                     //  8 MiB bf16 A (exact counts) [b][dst][src]
  short* hThi = (short*)(wb + 8388608);         //  8 MiB bf16 h^T hi [b][f][n]
  short* hTlo = (short*)(wb + 16777216);        //  8 MiB bf16 h^T lo
  short* hRhi = (short*)(wb + 25165824);        //  8 MiB bf16 h row-major hi [b][n][f]
  short* PtH  = (short*)(wb + 33554432);        //  4 MiB bf16 assign^T hi [b][k][n]
  short* PtL  = (short*)(wb + 37748736);        //  4 MiB
  short* FtH  = (short*)(wb + 41943040);        //  4 MiB bf16 feat^T hi [b][d][n]
  short* FtL  = (short*)(wb + 46137344);        //  4 MiB
  short* AStH = (short*)(wb + 50331648);        //  4 MiB bf16 (A@assign)^T hi [b][k][n]
  short* AStL = (short*)(wb + 54525952);        //  4 MiB
  float* deg  = (float*)(wb + 58720256);        // 64 KiB
  short* Wt   = (short*)(wb + 58785792);        // 256 KiB bf16 W^T

  k_prep<<<1312, 256, 0, stream>>>(h, esrc, edst, Wf, Wp, hThi, hTlo, hRhi, Abf, deg, Wt);
  k_fz<<<768, 256, 0, stream>>>(hRhi, Abf, hThi, hTlo, deg, Wt, bfe, bpo,
                                FtH, FtL, PtH, PtL, adj);
  k_gemm_as<<<896, 256, 0, stream>>>(Abf, PtH, PtL, FtH, FtL, AStH, AStL, hpool, adj);
  k_pool2<<<384, 256, 0, stream>>>(PtH, PtL, AStH, AStL, adj);
}